// Round 16
// baseline (192.994 us; speedup 1.0000x reference)
//
#include <hip/hip_runtime.h>
#include <math.h>

#define LEAKY 0.2f
#define SB 256
#define FTILE 4096

typedef _Float16 half2v __attribute__((ext_vector_type(2)));
typedef _Float16 half4 __attribute__((ext_vector_type(4)));
typedef _Float16 half8 __attribute__((ext_vector_type(8)));
typedef float f32x4 __attribute__((ext_vector_type(4)));

static inline int ceil_div(int a, int b) { return (a + b - 1) / b; }

// storage index p -> original column, for 64-col groups
__device__ __forceinline__ int PERM(int p) {
  int q = p & 63;
  return (p & ~63) | (((q & 3) << 4) | (q >> 2));
}

// ---------------- zero helper ----------------
__global__ __launch_bounds__(256) void k_zero(int4* __restrict__ buf, int n4) {
  int i = blockIdx.x * 256 + threadIdx.x;
  if (i < n4) buf[i] = make_int4(0, 0, 0, 0);
}

// ---- fillA: radix-partition edges into bucket-contiguous packed pairs ------
// pairs entry = (dst_rel << 20) | src  (dst_rel < chunk <= 4096, src < 2^20)
// two sweeps over ei (2nd is L2-hot): histogram, then write.
__global__ __launch_bounds__(256) void k_fillA(const int* __restrict__ ei,
                                               int* __restrict__ bcnt,
                                               unsigned* __restrict__ pairs,
                                               int NE, int N, int chunk, int cap) {
  __shared__ int hist[256], base[256], cnt2[256];
  int t = threadIdx.x;
  hist[t] = 0;
  cnt2[t] = 0;
  __syncthreads();
  int ET = NE + N;
  int e0 = blockIdx.x * FTILE;
  int e1 = min(e0 + FTILE, ET);
  for (int e = e0 + t; e < e1; e += 256) {
    int d = (e < NE) ? ei[NE + e] : (e - NE);
    atomicAdd(&hist[d / chunk], 1);
  }
  __syncthreads();
  if (hist[t] > 0) base[t] = t * cap + atomicAdd(&bcnt[t], hist[t]);
  __syncthreads();
  for (int e = e0 + t; e < e1; e += 256) {
    int s = (e < NE) ? ei[e] : (e - NE);
    int d = (e < NE) ? ei[NE + e] : (e - NE);
    int b = d / chunk;
    int r = atomicAdd(&cnt2[b], 1);
    pairs[base[b] + r] = ((unsigned)(d - b * chunk) << 20) | (unsigned)s;
  }
}

// ---- fillB2: inline bcnt scan + per-bucket local degree + off + csr scatter -
__global__ __launch_bounds__(256) void k_fillB2(const unsigned* __restrict__ pairs,
                                                const int* __restrict__ bcnt,
                                                int* __restrict__ off,
                                                int* __restrict__ csr, int N,
                                                int chunk, int cap) {
  __shared__ int sc[256], hist[256], cur[256];
  int b = blockIdx.x, t = threadIdx.x;
  int node0 = b * chunk;
  // inline exclusive scan of bcnt (all blocks redo it; 1 KB, L2-hot)
  int bv = bcnt[t];
  sc[t] = bv;
  __syncthreads();
  for (int o = 1; o < 256; o <<= 1) {
    int u = (t >= o) ? sc[t - o] : 0;
    __syncthreads();
    sc[t] += u;
    __syncthreads();
  }
  int bpre_b = sc[b] - bcnt[b];
  int total = sc[255];
  if (t == 0 && b == (N - 1) / chunk) off[N] = total;
  hist[t] = 0;
  __syncthreads();
  int i0 = b * cap, i1 = i0 + bcnt[b];
  for (int i = i0 + t; i < i1; i += 256)
    atomicAdd(&hist[pairs[i] >> 20], 1);
  __syncthreads();
  int v = hist[t];
  for (int o = 1; o < 256; o <<= 1) {
    int u = (t >= o) ? hist[t - o] : 0;
    __syncthreads();
    hist[t] += u;
    __syncthreads();
  }
  int ex = hist[t] - v + bpre_b;
  if (t < chunk && node0 + t < N) off[node0 + t] = ex;
  cur[t] = ex;
  __syncthreads();
  for (int i = i0 + t; i < i1; i += 256) {
    unsigned u = pairs[i];
    int pos = atomicAdd(&cur[u >> 20], 1);
    csr[pos] = (int)(u & 0xFFFFFu);
  }
}

// ---------------- prep: weight fragments + folded attention vectors ---------
__global__ __launch_bounds__(256) void k_prep(const float* __restrict__ W1,
                                              const float* __restrict__ W2,
                                              const float* __restrict__ a_src1,
                                              const float* __restrict__ a_dst1,
                                              const float* __restrict__ a_src2,
                                              const float* __restrict__ a_dst2,
                                              const float* __restrict__ b1,
                                              _Float16* __restrict__ w1hf,
                                              _Float16* __restrict__ w2f,
                                              float* __restrict__ wt1s,
                                              float* __restrict__ wt1d,
                                              float* __restrict__ b1p) {
  int idx = blockIdx.x * 256 + threadIdx.x;
  if (idx < 32768) {  // w1hf[h][ks][ct][l][i]
    int i = idx & 7, l = (idx >> 3) & 63, ct = (idx >> 9) & 3, ks = (idx >> 11) & 3,
        h = idx >> 13;
    int k = 32 * ks + 8 * (l >> 4) + i;
    int col = h * 64 + 16 * ct + (l & 15);
    w1hf[idx] = (_Float16)W1[k * 256 + col];
    return;
  }
  int i2 = idx - 32768;
  if (i2 < 16384) {  // w2f[ks][ct][l][i], A-side k' is layer-1 permuted index
    int i = i2 & 7, l = (i2 >> 3) & 63, ct = (i2 >> 9) & 3, ks = i2 >> 11;
    int kp = 32 * ks + 8 * (l >> 4) + i;
    int col = 16 * ct + (l & 15);
    w2f[i2] = (_Float16)W2[PERM(kp) * 64 + col];
    return;
  }
  int i3 = i2 - 16384;
  if (i3 < 512) {  // wt1s/wt1d[k*4+h]
    int h = i3 & 3, k = i3 >> 2;
    float ss = 0.f, sd = 0.f;
    for (int d = 0; d < 64; ++d) {
      float wv = W1[k * 256 + h * 64 + d];
      ss = fmaf(wv, a_src1[h * 64 + d], ss);
      sd = fmaf(wv, a_dst1[h * 64 + d], sd);
    }
    wt1s[i3] = ss;
    wt1d[i3] = sd;
    return;
  }
  int i4 = i3 - 512;
  if (i4 < 256) b1p[i4] = b1[PERM(i4)];
}

// ---------------- logits1: as1/ad1 = x @ wt1, also emit x16 -----------------
__global__ __launch_bounds__(256) void k_logits1(const float* __restrict__ x,
                                                 const float* __restrict__ wt1s,
                                                 const float* __restrict__ wt1d,
                                                 _Float16* __restrict__ x16,
                                                 float* __restrict__ as1,
                                                 float* __restrict__ ad1, int N) {
  int w = threadIdx.x >> 6, l = threadIdx.x & 63;
  int n = blockIdx.x * 4 + w;
  if (n >= N) return;
  float2 xv = *reinterpret_cast<const float2*>(x + (size_t)n * 128 + 2 * l);
  half2v xh;
  xh[0] = (_Float16)xv.x;
  xh[1] = (_Float16)xv.y;
  *reinterpret_cast<half2v*>(x16 + (size_t)n * 128 + 2 * l) = xh;
  float4 w0s = reinterpret_cast<const float4*>(wt1s)[2 * l];
  float4 w1s = reinterpret_cast<const float4*>(wt1s)[2 * l + 1];
  float4 w0d = reinterpret_cast<const float4*>(wt1d)[2 * l];
  float4 w1d = reinterpret_cast<const float4*>(wt1d)[2 * l + 1];
  float sa[4], sd[4];
  sa[0] = xv.x * w0s.x + xv.y * w1s.x;
  sa[1] = xv.x * w0s.y + xv.y * w1s.y;
  sa[2] = xv.x * w0s.z + xv.y * w1s.z;
  sa[3] = xv.x * w0s.w + xv.y * w1s.w;
  sd[0] = xv.x * w0d.x + xv.y * w1d.x;
  sd[1] = xv.x * w0d.y + xv.y * w1d.y;
  sd[2] = xv.x * w0d.z + xv.y * w1d.z;
  sd[3] = xv.x * w0d.w + xv.y * w1d.w;
#pragma unroll
  for (int o = 1; o <= 32; o <<= 1) {
#pragma unroll
    for (int h = 0; h < 4; ++h) {
      sa[h] += __shfl_xor(sa[h], o, 64);
      sd[h] += __shfl_xor(sd[h], o, 64);
    }
  }
  if (l == 0) {
#pragma unroll
    for (int h = 0; h < 4; ++h) {
      as1[n * 4 + h] = sa[h];
      ad1[n * 4 + h] = sd[h];
    }
  }
}

// ------- alpha1, 2-pass: UNNORMALIZED fp16 p + linv1 = 1/sum ---------------
__global__ __launch_bounds__(256) void k_alpha1(const float* __restrict__ as1,
                                                const float* __restrict__ ad1,
                                                const int* __restrict__ off,
                                                const int* __restrict__ csr,
                                                _Float16* __restrict__ alpha,
                                                float* __restrict__ linv1, int N) {
  int w = threadIdx.x >> 6, lane = threadIdx.x & 63;
  int n = blockIdx.x * 4 + w;
  if (n >= N) return;
  int eidx = lane >> 2, h = lane & 3;
  float adv = ad1[n * 4 + h];
  int e0 = off[n], e1 = off[n + 1];
  float m = -INFINITY;
  for (int base = e0; base < e1; base += 16) {
    int idx = base + eidx;
    if (idx < e1) {
      int s = csr[idx];
      float t = as1[s * 4 + h] + adv;
      t = t > 0.f ? t : LEAKY * t;
      m = fmaxf(m, t);
    }
  }
#pragma unroll
  for (int o = 4; o <= 32; o <<= 1) m = fmaxf(m, __shfl_xor(m, o, 64));
  float lp = 0.f;
  for (int base = e0; base < e1; base += 16) {
    int idx = base + eidx;
    if (idx < e1) {
      int s = csr[idx];
      float t = as1[s * 4 + h] + adv;
      t = t > 0.f ? t : LEAKY * t;
      float p = __expf(t - m);
      alpha[(size_t)idx * 4 + h] = (_Float16)p;
      lp += p;
    }
  }
#pragma unroll
  for (int o = 4; o <= 32; o <<= 1) lp += __shfl_xor(lp, o, 64);
  if (lane < 4) linv1[n * 4 + h] = 1.f / lp;
}

// ---------------- x-space aggregation: packed-fp16 accumulate, 32 edges deep -
// lane = slot*16 + kq; slot covers edge base+8u+slot... (4 slots x 8 unroll)
__global__ __launch_bounds__(256) void k_xagg(const _Float16* __restrict__ x16,
                                              const _Float16* __restrict__ alpha,
                                              const float* __restrict__ linv1,
                                              const int* __restrict__ off,
                                              const int* __restrict__ csr,
                                              _Float16* __restrict__ xagg, int N) {
  int w = threadIdx.x >> 6, l = threadIdx.x & 63;
  int n = blockIdx.x * 4 + w;
  if (n >= N) return;
  int slot = l >> 4, kq = l & 15;
  int e0 = off[n], e1 = off[n + 1];
  half2v acc[4][4];
#pragma unroll
  for (int h = 0; h < 4; ++h)
#pragma unroll
    for (int j = 0; j < 4; ++j) acc[h][j] = (half2v){(_Float16)0.f, (_Float16)0.f};
  const _Float16 zero16 = (_Float16)0.f;
  for (int base = e0; base < e1; base += 32) {
#pragma unroll
    for (int u = 0; u < 8; ++u) {
      int e = base + 4 * u + slot;
      int ec = min(e, e1 - 1);
      int src = csr[ec];
      half4 al = *reinterpret_cast<const half4*>(alpha + (size_t)ec * 4);
      if (e >= e1) al = (half4){zero16, zero16, zero16, zero16};
      half8 hv = *reinterpret_cast<const half8*>(x16 + (size_t)src * 128 + 8 * kq);
      half2v xp[4];
      xp[0] = (half2v){hv[0], hv[1]};
      xp[1] = (half2v){hv[2], hv[3]};
      xp[2] = (half2v){hv[4], hv[5]};
      xp[3] = (half2v){hv[6], hv[7]};
#pragma unroll
      for (int h = 0; h < 4; ++h) {
        half2v ah = (half2v){al[h], al[h]};
#pragma unroll
        for (int j = 0; j < 4; ++j) acc[h][j] = ah * xp[j] + acc[h][j];
      }
    }
  }
#pragma unroll
  for (int h = 0; h < 4; ++h)
#pragma unroll
    for (int j = 0; j < 4; ++j) {
      int v0 = __shfl_xor(__builtin_bit_cast(int, acc[h][j]), 16, 64);
      acc[h][j] = acc[h][j] + __builtin_bit_cast(half2v, v0);
      int v1 = __shfl_xor(__builtin_bit_cast(int, acc[h][j]), 32, 64);
      acc[h][j] = acc[h][j] + __builtin_bit_cast(half2v, v1);
    }
  if (slot == 0) {
    float4 linv = *reinterpret_cast<const float4*>(linv1 + n * 4);
    float rin[4] = {linv.x, linv.y, linv.z, linv.w};
#pragma unroll
    for (int h = 0; h < 4; ++h) {
      half8 o;
#pragma unroll
      for (int j = 0; j < 4; ++j) {
        o[2 * j] = (_Float16)((float)acc[h][j][0] * rin[h]);
        o[2 * j + 1] = (_Float16)((float)acc[h][j][1] * rin[h]);
      }
      *reinterpret_cast<half8*>(xagg + (size_t)n * 512 + h * 128 + 8 * kq) = o;
    }
  }
}

// -------- fused layer-1 + layer-2 GEMM: xagg -> (LDS) -> h2p, as2/ad2 --------
__global__ __launch_bounds__(256) void k_gemm12(const _Float16* __restrict__ xagg,
                                                const _Float16* __restrict__ w1hf,
                                                const _Float16* __restrict__ w2f,
                                                const float* __restrict__ b1p,
                                                const float* __restrict__ a_src2,
                                                const float* __restrict__ a_dst2,
                                                _Float16* __restrict__ h2p,
                                                float* __restrict__ as2,
                                                float* __restrict__ ad2, int N) {
  __shared__ _Float16 hs[64 * 256];  // 32 KiB
  int w = threadIdx.x >> 6, l = threadIdx.x & 63;
  int n0 = blockIdx.x * 64 + 16 * w;
  int lrow = l & 15, lgrp = l >> 4;
  int arow = min(n0 + lrow, N - 1);
  // ---- phase 1: gemm1 ----
  f32x4 acc1[4][4];
#pragma unroll
  for (int h = 0; h < 4; ++h)
#pragma unroll
    for (int ct = 0; ct < 4; ++ct) acc1[h][ct] = (f32x4){0.f, 0.f, 0.f, 0.f};
#pragma unroll
  for (int h = 0; h < 4; ++h) {
#pragma unroll
    for (int ks = 0; ks < 4; ++ks) {
      half8 af = *reinterpret_cast<const half8*>(xagg + (size_t)arow * 512 + h * 128 +
                                                 32 * ks + 8 * lgrp);
      const half8* bp =
          reinterpret_cast<const half8*>(w1hf) + (size_t)((h * 4 + ks) * 4) * 64 + l;
#pragma unroll
      for (int ct = 0; ct < 4; ++ct) {
        half8 bf = bp[ct * 64];
        acc1[h][ct] = __builtin_amdgcn_mfma_f32_16x16x32_f16(af, bf, acc1[h][ct], 0, 0, 0);
      }
    }
  }
  int lr0 = 16 * w + 4 * lgrp;
#pragma unroll
  for (int h = 0; h < 4; ++h) {
    float4 bv = *reinterpret_cast<const float4*>(b1p + h * 64 + lrow * 4);
#pragma unroll
    for (int r = 0; r < 4; ++r) {
      int row = lr0 + r;
      half4 o;
      o[0] = (_Float16)fmaxf(acc1[h][0][r] + bv.x, 0.f);
      o[1] = (_Float16)fmaxf(acc1[h][1][r] + bv.y, 0.f);
      o[2] = (_Float16)fmaxf(acc1[h][2][r] + bv.z, 0.f);
      o[3] = (_Float16)fmaxf(acc1[h][3][r] + bv.w, 0.f);
      int ba = row * 512 + ((h * 128 + lrow * 8) ^ ((row & 7) << 4));
      *reinterpret_cast<half4*>(reinterpret_cast<char*>(hs) + ba) = o;
    }
  }
  __syncthreads();
  // ---- phase 2: gemm2 over K=256 from LDS ----
  int arow2 = 16 * w + lrow;
  f32x4 acc2[4];
#pragma unroll
  for (int ct = 0; ct < 4; ++ct) acc2[ct] = (f32x4){0.f, 0.f, 0.f, 0.f};
#pragma unroll
  for (int ks = 0; ks < 8; ++ks) {
    int ba = arow2 * 512 + ((64 * ks + 16 * lgrp) ^ ((arow2 & 7) << 4));
    half8 af = *reinterpret_cast<const half8*>(reinterpret_cast<const char*>(hs) + ba);
    const half8* bp = reinterpret_cast<const half8*>(w2f) + (size_t)(ks * 4) * 64 + l;
#pragma unroll
    for (int ct = 0; ct < 4; ++ct) {
      half8 bf = bp[ct * 64];
      acc2[ct] = __builtin_amdgcn_mfma_f32_16x16x32_f16(af, bf, acc2[ct], 0, 0, 0);
    }
  }
  float ascol[4], adcol[4];
#pragma unroll
  for (int ct = 0; ct < 4; ++ct) {
    ascol[ct] = a_src2[16 * ct + lrow];
    adcol[ct] = a_dst2[16 * ct + lrow];
  }
  int rbase = n0 + 4 * lgrp;
#pragma unroll
  for (int r = 0; r < 4; ++r) {
    int row = rbase + r;
    bool ok = row < N;
    float sa = 0.f, sd = 0.f;
    half4 o;
#pragma unroll
    for (int ct = 0; ct < 4; ++ct) {
      float v = acc2[ct][r];
      o[ct] = (_Float16)v;
      sa = fmaf(v, ascol[ct], sa);
      sd = fmaf(v, adcol[ct], sd);
    }
    if (ok) *reinterpret_cast<half4*>(h2p + (size_t)row * 64 + lrow * 4) = o;
#pragma unroll
    for (int oo = 1; oo <= 8; oo <<= 1) {
      sa += __shfl_xor(sa, oo, 64);
      sd += __shfl_xor(sd, oo, 64);
    }
    if (ok && lrow == 0) {
      as2[row] = sa;
      ad2[row] = sd;
    }
  }
}

// ---------------- Layer 2: fused softmax + aggregation, 2-pass ---------------
__global__ __launch_bounds__(256) void k_agg2(const _Float16* __restrict__ h2p,
                                              const float* __restrict__ as2,
                                              const float* __restrict__ ad2,
                                              const float* __restrict__ b2,
                                              const int* __restrict__ off,
                                              const int* __restrict__ csr,
                                              float* __restrict__ out, int N) {
  int w = threadIdx.x >> 6, lane = threadIdx.x & 63;
  int n = blockIdx.x * 4 + w;
  if (n >= N) return;
  float adv = ad2[n];
  int e0 = off[n], e1 = off[n + 1];
  float m = -INFINITY;
  for (int idx = e0 + lane; idx < e1; idx += 64) {
    float t = as2[csr[idx]] + adv;
    t = t > 0.f ? t : LEAKY * t;
    m = fmaxf(m, t);
  }
#pragma unroll
  for (int o = 1; o <= 32; o <<= 1) m = fmaxf(m, __shfl_xor(m, o, 64));
  int slot = lane >> 3, q = lane & 7;
  float acc[8];
  float lp = 0.f;
#pragma unroll
  for (int k = 0; k < 8; ++k) acc[k] = 0.f;
  for (int base = e0; base < e1; base += 32) {
#pragma unroll
    for (int u = 0; u < 4; ++u) {
      int e = base + 8 * u + slot;
      int ec = min(e, e1 - 1);
      int s = csr[ec];
      float t = as2[s] + adv;
      t = t > 0.f ? t : LEAKY * t;
      float p = (e < e1) ? __expf(t - m) : 0.f;
      lp += p;
      half8 hv = *reinterpret_cast<const half8*>(h2p + (size_t)s * 64 + 8 * q);
#pragma unroll
      for (int k = 0; k < 8; ++k) acc[k] = fmaf(p, (float)hv[k], acc[k]);
    }
  }
#pragma unroll
  for (int o = 8; o <= 32; o <<= 1) {
    lp += __shfl_xor(lp, o, 64);
#pragma unroll
    for (int k = 0; k < 8; ++k) acc[k] += __shfl_xor(acc[k], o, 64);
  }
  if (slot == 0) {
    float rinv = 1.f / lp;
    // storage p = 8q + k  ->  orig col = ((k&3)<<4) | (2q + (k>>2))
#pragma unroll
    for (int k = 0; k < 8; ++k) {
      int col = ((k & 3) << 4) + 2 * q + (k >> 2);
      out[(size_t)n * 64 + col] = acc[k] * rinv + b2[col];
    }
  }
}

extern "C" void kernel_launch(void* const* d_in, const int* in_sizes, int n_in,
                              void* d_out, int out_size, void* d_ws, size_t ws_size,
                              hipStream_t stream) {
  const float* x = (const float*)d_in[0];
  const int* ei = (const int*)d_in[1];
  const float* W1 = (const float*)d_in[2];
  const float* a_src1 = (const float*)d_in[3];
  const float* a_dst1 = (const float*)d_in[4];
  const float* b1 = (const float*)d_in[5];
  const float* W2 = (const float*)d_in[6];
  const float* a_src2 = (const float*)d_in[7];
  const float* a_dst2 = (const float*)d_in[8];
  const float* b2 = (const float*)d_in[9];
  float* out = (float*)d_out;

  const int N = in_sizes[0] / 128;
  const int NE = in_sizes[1] / 2;
  const int ET = NE + N;
  const int chunk = ceil_div(N, SB);
  const int cap = 3 * ceil_div(ET, SB);

  char* p = (char*)d_ws;
  auto alloc = [&](size_t bytes) {
    char* r = p;
    p += (bytes + 255) & ~(size_t)255;
    return r;
  };
  int* bcnt = (int*)alloc((size_t)SB * 4);
  int* off = (int*)alloc((size_t)(N + 1) * 4);
  int* csr = (int*)alloc((size_t)ET * 4);
  unsigned* pairs = (unsigned*)alloc((size_t)SB * cap * 4);
  _Float16* w1hf = (_Float16*)alloc((size_t)32768 * 2);
  _Float16* w2f = (_Float16*)alloc((size_t)16384 * 2);
  float* wt1s = (float*)alloc((size_t)512 * 4);
  float* wt1d = (float*)alloc((size_t)512 * 4);
  float* b1p = (float*)alloc((size_t)256 * 4);
  _Float16* x16 = (_Float16*)alloc((size_t)N * 128 * 2);
  _Float16* xagg = (_Float16*)alloc((size_t)N * 512 * 2);
  float* as1 = (float*)alloc((size_t)N * 4 * 4);
  float* ad1 = (float*)alloc((size_t)N * 4 * 4);
  _Float16* alpha1 = (_Float16*)alloc((size_t)ET * 4 * 2);
  float* linv1 = (float*)alloc((size_t)N * 4 * 4);
  _Float16* h2p = x16;  // reuse: x16 dead after k_xagg
  float* as2 = (float*)alloc((size_t)N * 4);
  float* ad2 = (float*)alloc((size_t)N * 4);

  k_zero<<<1, 256, 0, stream>>>((int4*)bcnt, SB / 4);
  k_fillA<<<ceil_div(ET, FTILE), 256, 0, stream>>>(ei, bcnt, pairs, NE, N, chunk, cap);
  k_fillB2<<<SB, 256, 0, stream>>>(pairs, bcnt, off, csr, N, chunk, cap);
  k_prep<<<198, 256, 0, stream>>>(W1, W2, a_src1, a_dst1, a_src2, a_dst2, b1,
                                  w1hf, w2f, wt1s, wt1d, b1p);

  k_logits1<<<ceil_div(N, 4), 256, 0, stream>>>(x, wt1s, wt1d, x16, as1, ad1, N);
  k_alpha1<<<ceil_div(N, 4), 256, 0, stream>>>(as1, ad1, off, csr, alpha1, linv1, N);
  k_xagg<<<ceil_div(N, 4), 256, 0, stream>>>(x16, alpha1, linv1, off, csr, xagg, N);
  k_gemm12<<<ceil_div(N, 64), 256, 0, stream>>>(xagg, w1hf, w2f, b1p, a_src2,
                                                a_dst2, h2p, as2, ad2, N);
  k_agg2<<<ceil_div(N, 4), 256, 0, stream>>>(h2p, as2, ad2, b2, off, csr, out, N);
}

// Round 17
// 186.915 us; speedup vs baseline: 1.0325x; 1.0325x over previous
//
#include <hip/hip_runtime.h>
#include <math.h>

#define LEAKY 0.2f
#define SB 256
#define FTILE 4096

typedef _Float16 half2v __attribute__((ext_vector_type(2)));
typedef _Float16 half4 __attribute__((ext_vector_type(4)));
typedef _Float16 half8 __attribute__((ext_vector_type(8)));
typedef float f32x4 __attribute__((ext_vector_type(4)));

static inline int ceil_div(int a, int b) { return (a + b - 1) / b; }

// storage index p -> original column, for 64-col groups
__device__ __forceinline__ int PERM(int p) {
  int q = p & 63;
  return (p & ~63) | (((q & 3) << 4) | (q >> 2));
}

// ---------------- zero helper ----------------
__global__ __launch_bounds__(256) void k_zero(int4* __restrict__ buf, int n4) {
  int i = blockIdx.x * 256 + threadIdx.x;
  if (i < n4) buf[i] = make_int4(0, 0, 0, 0);
}

// ---- fillA: radix-partition edges into bucket-contiguous packed pairs ------
__global__ __launch_bounds__(256) void k_fillA(const int* __restrict__ ei,
                                               int* __restrict__ bcnt,
                                               unsigned* __restrict__ pairs,
                                               int NE, int N, int chunk, int cap) {
  __shared__ int hist[256], base[256], cnt2[256];
  int t = threadIdx.x;
  hist[t] = 0;
  cnt2[t] = 0;
  __syncthreads();
  int ET = NE + N;
  int e0 = blockIdx.x * FTILE;
  int e1 = min(e0 + FTILE, ET);
  for (int e = e0 + t; e < e1; e += 256) {
    int d = (e < NE) ? ei[NE + e] : (e - NE);
    atomicAdd(&hist[d / chunk], 1);
  }
  __syncthreads();
  if (hist[t] > 0) base[t] = t * cap + atomicAdd(&bcnt[t], hist[t]);
  __syncthreads();
  for (int e = e0 + t; e < e1; e += 256) {
    int s = (e < NE) ? ei[e] : (e - NE);
    int d = (e < NE) ? ei[NE + e] : (e - NE);
    int b = d / chunk;
    int r = atomicAdd(&cnt2[b], 1);
    pairs[base[b] + r] = ((unsigned)(d - b * chunk) << 20) | (unsigned)s;
  }
}

// ---- fillB2: inline bcnt scan + per-bucket local degree + off + csr scatter -
__global__ __launch_bounds__(256) void k_fillB2(const unsigned* __restrict__ pairs,
                                                const int* __restrict__ bcnt,
                                                int* __restrict__ off,
                                                int* __restrict__ csr, int N,
                                                int chunk, int cap) {
  __shared__ int sc[256], hist[256], cur[256];
  int b = blockIdx.x, t = threadIdx.x;
  int node0 = b * chunk;
  int bv = bcnt[t];
  sc[t] = bv;
  __syncthreads();
  for (int o = 1; o < 256; o <<= 1) {
    int u = (t >= o) ? sc[t - o] : 0;
    __syncthreads();
    sc[t] += u;
    __syncthreads();
  }
  int bpre_b = sc[b] - bcnt[b];
  int total = sc[255];
  if (t == 0 && b == (N - 1) / chunk) off[N] = total;
  hist[t] = 0;
  __syncthreads();
  int i0 = b * cap, i1 = i0 + bcnt[b];
  for (int i = i0 + t; i < i1; i += 256)
    atomicAdd(&hist[pairs[i] >> 20], 1);
  __syncthreads();
  int v = hist[t];
  for (int o = 1; o < 256; o <<= 1) {
    int u = (t >= o) ? hist[t - o] : 0;
    __syncthreads();
    hist[t] += u;
    __syncthreads();
  }
  int ex = hist[t] - v + bpre_b;
  if (t < chunk && node0 + t < N) off[node0 + t] = ex;
  cur[t] = ex;
  __syncthreads();
  for (int i = i0 + t; i < i1; i += 256) {
    unsigned u = pairs[i];
    int pos = atomicAdd(&cur[u >> 20], 1);
    csr[pos] = (int)(u & 0xFFFFFu);
  }
}

// ---------------- prep: weight fragments + folded attention vectors ---------
__global__ __launch_bounds__(256) void k_prep(const float* __restrict__ W1,
                                              const float* __restrict__ W2,
                                              const float* __restrict__ a_src1,
                                              const float* __restrict__ a_dst1,
                                              const float* __restrict__ a_src2,
                                              const float* __restrict__ a_dst2,
                                              const float* __restrict__ b1,
                                              _Float16* __restrict__ w1hf,
                                              _Float16* __restrict__ w2f,
                                              float* __restrict__ wt1s,
                                              float* __restrict__ wt1d,
                                              float* __restrict__ b1p) {
  int idx = blockIdx.x * 256 + threadIdx.x;
  if (idx < 32768) {  // w1hf[h][ks][ct][l][i]
    int i = idx & 7, l = (idx >> 3) & 63, ct = (idx >> 9) & 3, ks = (idx >> 11) & 3,
        h = idx >> 13;
    int k = 32 * ks + 8 * (l >> 4) + i;
    int col = h * 64 + 16 * ct + (l & 15);
    w1hf[idx] = (_Float16)W1[k * 256 + col];
    return;
  }
  int i2 = idx - 32768;
  if (i2 < 16384) {  // w2f[ks][ct][l][i], A-side k' is layer-1 permuted index
    int i = i2 & 7, l = (i2 >> 3) & 63, ct = (i2 >> 9) & 3, ks = i2 >> 11;
    int kp = 32 * ks + 8 * (l >> 4) + i;
    int col = 16 * ct + (l & 15);
    w2f[i2] = (_Float16)W2[PERM(kp) * 64 + col];
    return;
  }
  int i3 = i2 - 16384;
  if (i3 < 512) {  // wt1s/wt1d[k*4+h]
    int h = i3 & 3, k = i3 >> 2;
    float ss = 0.f, sd = 0.f;
    for (int d = 0; d < 64; ++d) {
      float wv = W1[k * 256 + h * 64 + d];
      ss = fmaf(wv, a_src1[h * 64 + d], ss);
      sd = fmaf(wv, a_dst1[h * 64 + d], sd);
    }
    wt1s[i3] = ss;
    wt1d[i3] = sd;
    return;
  }
  int i4 = i3 - 512;
  if (i4 < 256) b1p[i4] = b1[PERM(i4)];
}

// ---------------- logits1: as1/ad1 = x @ wt1, also emit x16 -----------------
__global__ __launch_bounds__(256) void k_logits1(const float* __restrict__ x,
                                                 const float* __restrict__ wt1s,
                                                 const float* __restrict__ wt1d,
                                                 _Float16* __restrict__ x16,
                                                 float* __restrict__ as1,
                                                 float* __restrict__ ad1, int N) {
  int w = threadIdx.x >> 6, l = threadIdx.x & 63;
  int n = blockIdx.x * 4 + w;
  if (n >= N) return;
  float2 xv = *reinterpret_cast<const float2*>(x + (size_t)n * 128 + 2 * l);
  half2v xh;
  xh[0] = (_Float16)xv.x;
  xh[1] = (_Float16)xv.y;
  *reinterpret_cast<half2v*>(x16 + (size_t)n * 128 + 2 * l) = xh;
  float4 w0s = reinterpret_cast<const float4*>(wt1s)[2 * l];
  float4 w1s = reinterpret_cast<const float4*>(wt1s)[2 * l + 1];
  float4 w0d = reinterpret_cast<const float4*>(wt1d)[2 * l];
  float4 w1d = reinterpret_cast<const float4*>(wt1d)[2 * l + 1];
  float sa[4], sd[4];
  sa[0] = xv.x * w0s.x + xv.y * w1s.x;
  sa[1] = xv.x * w0s.y + xv.y * w1s.y;
  sa[2] = xv.x * w0s.z + xv.y * w1s.z;
  sa[3] = xv.x * w0s.w + xv.y * w1s.w;
  sd[0] = xv.x * w0d.x + xv.y * w1d.x;
  sd[1] = xv.x * w0d.y + xv.y * w1d.y;
  sd[2] = xv.x * w0d.z + xv.y * w1d.z;
  sd[3] = xv.x * w0d.w + xv.y * w1d.w;
#pragma unroll
  for (int o = 1; o <= 32; o <<= 1) {
#pragma unroll
    for (int h = 0; h < 4; ++h) {
      sa[h] += __shfl_xor(sa[h], o, 64);
      sd[h] += __shfl_xor(sd[h], o, 64);
    }
  }
  if (l == 0) {
#pragma unroll
    for (int h = 0; h < 4; ++h) {
      as1[n * 4 + h] = sa[h];
      ad1[n * 4 + h] = sd[h];
    }
  }
}

// ------- alpha1, 2-pass: UNNORMALIZED fp16 p + linv1 = 1/sum ---------------
__global__ __launch_bounds__(256) void k_alpha1(const float* __restrict__ as1,
                                                const float* __restrict__ ad1,
                                                const int* __restrict__ off,
                                                const int* __restrict__ csr,
                                                _Float16* __restrict__ alpha,
                                                float* __restrict__ linv1, int N) {
  int w = threadIdx.x >> 6, lane = threadIdx.x & 63;
  int n = blockIdx.x * 4 + w;
  if (n >= N) return;
  int eidx = lane >> 2, h = lane & 3;
  float adv = ad1[n * 4 + h];
  int e0 = off[n], e1 = off[n + 1];
  float m = -INFINITY;
  for (int base = e0; base < e1; base += 16) {
    int idx = base + eidx;
    if (idx < e1) {
      int s = csr[idx];
      float t = as1[s * 4 + h] + adv;
      t = t > 0.f ? t : LEAKY * t;
      m = fmaxf(m, t);
    }
  }
#pragma unroll
  for (int o = 4; o <= 32; o <<= 1) m = fmaxf(m, __shfl_xor(m, o, 64));
  float lp = 0.f;
  for (int base = e0; base < e1; base += 16) {
    int idx = base + eidx;
    if (idx < e1) {
      int s = csr[idx];
      float t = as1[s * 4 + h] + adv;
      t = t > 0.f ? t : LEAKY * t;
      float p = __expf(t - m);
      alpha[(size_t)idx * 4 + h] = (_Float16)p;
      lp += p;
    }
  }
#pragma unroll
  for (int o = 4; o <= 32; o <<= 1) lp += __shfl_xor(lp, o, 64);
  if (lane < 4) linv1[n * 4 + h] = 1.f / lp;
}

// ---------------- x-space aggregation: packed-fp16 accumulate, 16 edges deep -
// lane = slot*16 + kq; slot covers edge base+4u+slot, kq covers k = 8kq..8kq+7
__global__ __launch_bounds__(256) void k_xagg(const _Float16* __restrict__ x16,
                                              const _Float16* __restrict__ alpha,
                                              const float* __restrict__ linv1,
                                              const int* __restrict__ off,
                                              const int* __restrict__ csr,
                                              _Float16* __restrict__ xagg, int N) {
  int w = threadIdx.x >> 6, l = threadIdx.x & 63;
  int n = blockIdx.x * 4 + w;
  if (n >= N) return;
  int slot = l >> 4, kq = l & 15;
  int e0 = off[n], e1 = off[n + 1];
  half2v acc[4][4];
#pragma unroll
  for (int h = 0; h < 4; ++h)
#pragma unroll
    for (int j = 0; j < 4; ++j) acc[h][j] = (half2v){(_Float16)0.f, (_Float16)0.f};
  const _Float16 zero16 = (_Float16)0.f;
  for (int base = e0; base < e1; base += 16) {
#pragma unroll
    for (int u = 0; u < 4; ++u) {
      int e = base + 4 * u + slot;
      int ec = min(e, e1 - 1);
      int src = csr[ec];
      half4 al = *reinterpret_cast<const half4*>(alpha + (size_t)ec * 4);
      if (e >= e1) al = (half4){zero16, zero16, zero16, zero16};
      half8 hv = *reinterpret_cast<const half8*>(x16 + (size_t)src * 128 + 8 * kq);
      half2v xp[4];
      xp[0] = (half2v){hv[0], hv[1]};
      xp[1] = (half2v){hv[2], hv[3]};
      xp[2] = (half2v){hv[4], hv[5]};
      xp[3] = (half2v){hv[6], hv[7]};
#pragma unroll
      for (int h = 0; h < 4; ++h) {
        half2v ah = (half2v){al[h], al[h]};
#pragma unroll
        for (int j = 0; j < 4; ++j) acc[h][j] = ah * xp[j] + acc[h][j];
      }
    }
  }
#pragma unroll
  for (int h = 0; h < 4; ++h)
#pragma unroll
    for (int j = 0; j < 4; ++j) {
      int v0 = __shfl_xor(__builtin_bit_cast(int, acc[h][j]), 16, 64);
      acc[h][j] = acc[h][j] + __builtin_bit_cast(half2v, v0);
      int v1 = __shfl_xor(__builtin_bit_cast(int, acc[h][j]), 32, 64);
      acc[h][j] = acc[h][j] + __builtin_bit_cast(half2v, v1);
    }
  if (slot == 0) {
    float4 linv = *reinterpret_cast<const float4*>(linv1 + n * 4);
    float rin[4] = {linv.x, linv.y, linv.z, linv.w};
#pragma unroll
    for (int h = 0; h < 4; ++h) {
      half8 o;
#pragma unroll
      for (int j = 0; j < 4; ++j) {
        o[2 * j] = (_Float16)((float)acc[h][j][0] * rin[h]);
        o[2 * j + 1] = (_Float16)((float)acc[h][j][1] * rin[h]);
      }
      *reinterpret_cast<half8*>(xagg + (size_t)n * 512 + h * 128 + 8 * kq) = o;
    }
  }
}

// -------- fused layer-1 + layer-2 GEMM: xagg -> (LDS) -> h2p, as2/ad2 --------
__global__ __launch_bounds__(256) void k_gemm12(const _Float16* __restrict__ xagg,
                                                const _Float16* __restrict__ w1hf,
                                                const _Float16* __restrict__ w2f,
                                                const float* __restrict__ b1p,
                                                const float* __restrict__ a_src2,
                                                const float* __restrict__ a_dst2,
                                                _Float16* __restrict__ h2p,
                                                float* __restrict__ as2,
                                                float* __restrict__ ad2, int N) {
  __shared__ _Float16 hs[64 * 256];  // 32 KiB
  int w = threadIdx.x >> 6, l = threadIdx.x & 63;
  int n0 = blockIdx.x * 64 + 16 * w;
  int lrow = l & 15, lgrp = l >> 4;
  int arow = min(n0 + lrow, N - 1);
  // ---- phase 1: gemm1 ----
  f32x4 acc1[4][4];
#pragma unroll
  for (int h = 0; h < 4; ++h)
#pragma unroll
    for (int ct = 0; ct < 4; ++ct) acc1[h][ct] = (f32x4){0.f, 0.f, 0.f, 0.f};
#pragma unroll
  for (int h = 0; h < 4; ++h) {
#pragma unroll
    for (int ks = 0; ks < 4; ++ks) {
      half8 af = *reinterpret_cast<const half8*>(xagg + (size_t)arow * 512 + h * 128 +
                                                 32 * ks + 8 * lgrp);
      const half8* bp =
          reinterpret_cast<const half8*>(w1hf) + (size_t)((h * 4 + ks) * 4) * 64 + l;
#pragma unroll
      for (int ct = 0; ct < 4; ++ct) {
        half8 bf = bp[ct * 64];
        acc1[h][ct] = __builtin_amdgcn_mfma_f32_16x16x32_f16(af, bf, acc1[h][ct], 0, 0, 0);
      }
    }
  }
  int lr0 = 16 * w + 4 * lgrp;
#pragma unroll
  for (int h = 0; h < 4; ++h) {
    float4 bv = *reinterpret_cast<const float4*>(b1p + h * 64 + lrow * 4);
#pragma unroll
    for (int r = 0; r < 4; ++r) {
      int row = lr0 + r;
      half4 o;
      o[0] = (_Float16)fmaxf(acc1[h][0][r] + bv.x, 0.f);
      o[1] = (_Float16)fmaxf(acc1[h][1][r] + bv.y, 0.f);
      o[2] = (_Float16)fmaxf(acc1[h][2][r] + bv.z, 0.f);
      o[3] = (_Float16)fmaxf(acc1[h][3][r] + bv.w, 0.f);
      int ba = row * 512 + ((h * 128 + lrow * 8) ^ ((row & 7) << 4));
      *reinterpret_cast<half4*>(reinterpret_cast<char*>(hs) + ba) = o;
    }
  }
  __syncthreads();
  // ---- phase 2: gemm2 over K=256 from LDS ----
  int arow2 = 16 * w + lrow;
  f32x4 acc2[4];
#pragma unroll
  for (int ct = 0; ct < 4; ++ct) acc2[ct] = (f32x4){0.f, 0.f, 0.f, 0.f};
#pragma unroll
  for (int ks = 0; ks < 8; ++ks) {
    int ba = arow2 * 512 + ((64 * ks + 16 * lgrp) ^ ((arow2 & 7) << 4));
    half8 af = *reinterpret_cast<const half8*>(reinterpret_cast<const char*>(hs) + ba);
    const half8* bp = reinterpret_cast<const half8*>(w2f) + (size_t)(ks * 4) * 64 + l;
#pragma unroll
    for (int ct = 0; ct < 4; ++ct) {
      half8 bf = bp[ct * 64];
      acc2[ct] = __builtin_amdgcn_mfma_f32_16x16x32_f16(af, bf, acc2[ct], 0, 0, 0);
    }
  }
  float ascol[4], adcol[4];
#pragma unroll
  for (int ct = 0; ct < 4; ++ct) {
    ascol[ct] = a_src2[16 * ct + lrow];
    adcol[ct] = a_dst2[16 * ct + lrow];
  }
  int rbase = n0 + 4 * lgrp;
#pragma unroll
  for (int r = 0; r < 4; ++r) {
    int row = rbase + r;
    bool ok = row < N;
    float sa = 0.f, sd = 0.f;
    half4 o;
#pragma unroll
    for (int ct = 0; ct < 4; ++ct) {
      float v = acc2[ct][r];
      o[ct] = (_Float16)v;
      sa = fmaf(v, ascol[ct], sa);
      sd = fmaf(v, adcol[ct], sd);
    }
    if (ok) *reinterpret_cast<half4*>(h2p + (size_t)row * 64 + lrow * 4) = o;
#pragma unroll
    for (int oo = 1; oo <= 8; oo <<= 1) {
      sa += __shfl_xor(sa, oo, 64);
      sd += __shfl_xor(sd, oo, 64);
    }
    if (ok && lrow == 0) {
      as2[row] = sa;
      ad2[row] = sd;
    }
  }
}

// ---------------- Layer 2: fused softmax + aggregation, 2-pass ---------------
__global__ __launch_bounds__(256) void k_agg2(const _Float16* __restrict__ h2p,
                                              const float* __restrict__ as2,
                                              const float* __restrict__ ad2,
                                              const float* __restrict__ b2,
                                              const int* __restrict__ off,
                                              const int* __restrict__ csr,
                                              float* __restrict__ out, int N) {
  int w = threadIdx.x >> 6, lane = threadIdx.x & 63;
  int n = blockIdx.x * 4 + w;
  if (n >= N) return;
  float adv = ad2[n];
  int e0 = off[n], e1 = off[n + 1];
  float m = -INFINITY;
  for (int idx = e0 + lane; idx < e1; idx += 64) {
    float t = as2[csr[idx]] + adv;
    t = t > 0.f ? t : LEAKY * t;
    m = fmaxf(m, t);
  }
#pragma unroll
  for (int o = 1; o <= 32; o <<= 1) m = fmaxf(m, __shfl_xor(m, o, 64));
  int slot = lane >> 3, q = lane & 7;
  float acc[8];
  float lp = 0.f;
#pragma unroll
  for (int k = 0; k < 8; ++k) acc[k] = 0.f;
  for (int base = e0; base < e1; base += 16) {
#pragma unroll
    for (int u = 0; u < 2; ++u) {
      int e = base + 8 * u + slot;
      int ec = min(e, e1 - 1);
      int s = csr[ec];
      float t = as2[s] + adv;
      t = t > 0.f ? t : LEAKY * t;
      float p = (e < e1) ? __expf(t - m) : 0.f;
      lp += p;
      half8 hv = *reinterpret_cast<const half8*>(h2p + (size_t)s * 64 + 8 * q);
#pragma unroll
      for (int k = 0; k < 8; ++k) acc[k] = fmaf(p, (float)hv[k], acc[k]);
    }
  }
#pragma unroll
  for (int o = 8; o <= 32; o <<= 1) {
    lp += __shfl_xor(lp, o, 64);
#pragma unroll
    for (int k = 0; k < 8; ++k) acc[k] += __shfl_xor(acc[k], o, 64);
  }
  if (slot == 0) {
    float rinv = 1.f / lp;
    // storage p = 8q + k  ->  orig col = ((k&3)<<4) | (2q + (k>>2))
#pragma unroll
    for (int k = 0; k < 8; ++k) {
      int col = ((k & 3) << 4) + 2 * q + (k >> 2);
      out[(size_t)n * 64 + col] = acc[k] * rinv + b2[col];
    }
  }
}

extern "C" void kernel_launch(void* const* d_in, const int* in_sizes, int n_in,
                              void* d_out, int out_size, void* d_ws, size_t ws_size,
                              hipStream_t stream) {
  const float* x = (const float*)d_in[0];
  const int* ei = (const int*)d_in[1];
  const float* W1 = (const float*)d_in[2];
  const float* a_src1 = (const float*)d_in[3];
  const float* a_dst1 = (const float*)d_in[4];
  const float* b1 = (const float*)d_in[5];
  const float* W2 = (const float*)d_in[6];
  const float* a_src2 = (const float*)d_in[7];
  const float* a_dst2 = (const float*)d_in[8];
  const float* b2 = (const float*)d_in[9];
  float* out = (float*)d_out;

  const int N = in_sizes[0] / 128;
  const int NE = in_sizes[1] / 2;
  const int ET = NE + N;
  const int chunk = ceil_div(N, SB);
  const int cap = 3 * ceil_div(ET, SB);

  char* p = (char*)d_ws;
  auto alloc = [&](size_t bytes) {
    char* r = p;
    p += (bytes + 255) & ~(size_t)255;
    return r;
  };
  int* bcnt = (int*)alloc((size_t)SB * 4);
  int* off = (int*)alloc((size_t)(N + 1) * 4);
  int* csr = (int*)alloc((size_t)ET * 4);
  unsigned* pairs = (unsigned*)alloc((size_t)SB * cap * 4);
  _Float16* w1hf = (_Float16*)alloc((size_t)32768 * 2);
  _Float16* w2f = (_Float16*)alloc((size_t)16384 * 2);
  float* wt1s = (float*)alloc((size_t)512 * 4);
  float* wt1d = (float*)alloc((size_t)512 * 4);
  float* b1p = (float*)alloc((size_t)256 * 4);
  _Float16* x16 = (_Float16*)alloc((size_t)N * 128 * 2);
  _Float16* xagg = (_Float16*)alloc((size_t)N * 512 * 2);
  float* as1 = (float*)alloc((size_t)N * 4 * 4);
  float* ad1 = (float*)alloc((size_t)N * 4 * 4);
  _Float16* alpha1 = (_Float16*)alloc((size_t)ET * 4 * 2);
  float* linv1 = (float*)alloc((size_t)N * 4 * 4);
  _Float16* h2p = x16;  // reuse: x16 dead after k_xagg
  float* as2 = (float*)alloc((size_t)N * 4);
  float* ad2 = (float*)alloc((size_t)N * 4);

  k_zero<<<1, 256, 0, stream>>>((int4*)bcnt, SB / 4);
  k_fillA<<<ceil_div(ET, FTILE), 256, 0, stream>>>(ei, bcnt, pairs, NE, N, chunk, cap);
  k_fillB2<<<SB, 256, 0, stream>>>(pairs, bcnt, off, csr, N, chunk, cap);
  k_prep<<<198, 256, 0, stream>>>(W1, W2, a_src1, a_dst1, a_src2, a_dst2, b1,
                                  w1hf, w2f, wt1s, wt1d, b1p);

  k_logits1<<<ceil_div(N, 4), 256, 0, stream>>>(x, wt1s, wt1d, x16, as1, ad1, N);
  k_alpha1<<<ceil_div(N, 4), 256, 0, stream>>>(as1, ad1, off, csr, alpha1, linv1, N);
  k_xagg<<<ceil_div(N, 4), 256, 0, stream>>>(x16, alpha1, linv1, off, csr, xagg, N);
  k_gemm12<<<ceil_div(N, 64), 256, 0, stream>>>(xagg, w1hf, w2f, b1p, a_src2,
                                                a_dst2, h2p, as2, ad2, N);
  k_agg2<<<ceil_div(N, 4), 256, 0, stream>>>(h2p, as2, ad2, b2, off, csr, out, N);
}

// Round 18
// 177.742 us; speedup vs baseline: 1.0858x; 1.0516x over previous
//
#include <hip/hip_runtime.h>
#include <math.h>

#define LEAKY 0.2f
#define SB 256
#define FTILE 4096
#define LN16 2.7725887f

typedef _Float16 half2v __attribute__((ext_vector_type(2)));
typedef _Float16 half4 __attribute__((ext_vector_type(4)));
typedef _Float16 half8 __attribute__((ext_vector_type(8)));
typedef float f32x4 __attribute__((ext_vector_type(4)));

static inline int ceil_div(int a, int b) { return (a + b - 1) / b; }

// storage index p -> original column, for 64-col groups
__device__ __forceinline__ int PERM(int p) {
  int q = p & 63;
  return (p & ~63) | (((q & 3) << 4) | (q >> 2));
}

// ---------------- zero helper ----------------
__global__ __launch_bounds__(256) void k_zero(int4* __restrict__ buf, int n4) {
  int i = blockIdx.x * 256 + threadIdx.x;
  if (i < n4) buf[i] = make_int4(0, 0, 0, 0);
}

// ---- fillA: radix-partition edges into bucket-contiguous packed pairs ------
__global__ __launch_bounds__(256) void k_fillA(const int* __restrict__ ei,
                                               int* __restrict__ bcnt,
                                               unsigned* __restrict__ pairs,
                                               int NE, int N, int chunk, int cap) {
  __shared__ int hist[256], base[256], cnt2[256];
  int t = threadIdx.x;
  hist[t] = 0;
  cnt2[t] = 0;
  __syncthreads();
  int ET = NE + N;
  int e0 = blockIdx.x * FTILE;
  int e1 = min(e0 + FTILE, ET);
  for (int e = e0 + t; e < e1; e += 256) {
    int d = (e < NE) ? ei[NE + e] : (e - NE);
    atomicAdd(&hist[d / chunk], 1);
  }
  __syncthreads();
  if (hist[t] > 0) base[t] = t * cap + atomicAdd(&bcnt[t], hist[t]);
  __syncthreads();
  for (int e = e0 + t; e < e1; e += 256) {
    int s = (e < NE) ? ei[e] : (e - NE);
    int d = (e < NE) ? ei[NE + e] : (e - NE);
    int b = d / chunk;
    int r = atomicAdd(&cnt2[b], 1);
    pairs[base[b] + r] = ((unsigned)(d - b * chunk) << 20) | (unsigned)s;
  }
}

// ---- fillB2: inline bcnt scan + per-bucket local degree + off + csr scatter -
__global__ __launch_bounds__(256) void k_fillB2(const unsigned* __restrict__ pairs,
                                                const int* __restrict__ bcnt,
                                                int* __restrict__ off,
                                                int* __restrict__ csr, int N,
                                                int chunk, int cap) {
  __shared__ int sc[256], hist[256], cur[256];
  int b = blockIdx.x, t = threadIdx.x;
  int node0 = b * chunk;
  int bv = bcnt[t];
  sc[t] = bv;
  __syncthreads();
  for (int o = 1; o < 256; o <<= 1) {
    int u = (t >= o) ? sc[t - o] : 0;
    __syncthreads();
    sc[t] += u;
    __syncthreads();
  }
  int bpre_b = sc[b] - bcnt[b];
  int total = sc[255];
  if (t == 0 && b == (N - 1) / chunk) off[N] = total;
  hist[t] = 0;
  __syncthreads();
  int i0 = b * cap, i1 = i0 + bcnt[b];
  for (int i = i0 + t; i < i1; i += 256)
    atomicAdd(&hist[pairs[i] >> 20], 1);
  __syncthreads();
  int v = hist[t];
  for (int o = 1; o < 256; o <<= 1) {
    int u = (t >= o) ? hist[t - o] : 0;
    __syncthreads();
    hist[t] += u;
    __syncthreads();
  }
  int ex = hist[t] - v + bpre_b;
  if (t < chunk && node0 + t < N) off[node0 + t] = ex;
  cur[t] = ex;
  __syncthreads();
  for (int i = i0 + t; i < i1; i += 256) {
    unsigned u = pairs[i];
    int pos = atomicAdd(&cur[u >> 20], 1);
    csr[pos] = (int)(u & 0xFFFFFu);
  }
}

// ---------------- prep: weight fragments + folded attention vectors ---------
__global__ __launch_bounds__(256) void k_prep(const float* __restrict__ W1,
                                              const float* __restrict__ W2,
                                              const float* __restrict__ a_src1,
                                              const float* __restrict__ a_dst1,
                                              const float* __restrict__ a_src2,
                                              const float* __restrict__ a_dst2,
                                              const float* __restrict__ b1,
                                              _Float16* __restrict__ w1hf,
                                              _Float16* __restrict__ w2f,
                                              float* __restrict__ wt1s,
                                              float* __restrict__ wt1d,
                                              float* __restrict__ b1p) {
  int idx = blockIdx.x * 256 + threadIdx.x;
  if (idx < 32768) {  // w1hf[h][ks][ct][l][i]
    int i = idx & 7, l = (idx >> 3) & 63, ct = (idx >> 9) & 3, ks = (idx >> 11) & 3,
        h = idx >> 13;
    int k = 32 * ks + 8 * (l >> 4) + i;
    int col = h * 64 + 16 * ct + (l & 15);
    w1hf[idx] = (_Float16)W1[k * 256 + col];
    return;
  }
  int i2 = idx - 32768;
  if (i2 < 16384) {  // w2f[ks][ct][l][i], A-side k' is layer-1 permuted index
    int i = i2 & 7, l = (i2 >> 3) & 63, ct = (i2 >> 9) & 3, ks = i2 >> 11;
    int kp = 32 * ks + 8 * (l >> 4) + i;
    int col = 16 * ct + (l & 15);
    w2f[i2] = (_Float16)W2[PERM(kp) * 64 + col];
    return;
  }
  int i3 = i2 - 16384;
  if (i3 < 512) {  // wt1s/wt1d[k*4+h]
    int h = i3 & 3, k = i3 >> 2;
    float ss = 0.f, sd = 0.f;
    for (int d = 0; d < 64; ++d) {
      float wv = W1[k * 256 + h * 64 + d];
      ss = fmaf(wv, a_src1[h * 64 + d], ss);
      sd = fmaf(wv, a_dst1[h * 64 + d], sd);
    }
    wt1s[i3] = ss;
    wt1d[i3] = sd;
    return;
  }
  int i4 = i3 - 512;
  if (i4 < 256) b1p[i4] = b1[PERM(i4)];
}

// ---------------- logits1: as1/ad1 = x @ wt1, also emit x16 -----------------
__global__ __launch_bounds__(256) void k_logits1(const float* __restrict__ x,
                                                 const float* __restrict__ wt1s,
                                                 const float* __restrict__ wt1d,
                                                 _Float16* __restrict__ x16,
                                                 float* __restrict__ as1,
                                                 float* __restrict__ ad1, int N) {
  int w = threadIdx.x >> 6, l = threadIdx.x & 63;
  int n = blockIdx.x * 4 + w;
  if (n >= N) return;
  float2 xv = *reinterpret_cast<const float2*>(x + (size_t)n * 128 + 2 * l);
  half2v xh;
  xh[0] = (_Float16)xv.x;
  xh[1] = (_Float16)xv.y;
  *reinterpret_cast<half2v*>(x16 + (size_t)n * 128 + 2 * l) = xh;
  float4 w0s = reinterpret_cast<const float4*>(wt1s)[2 * l];
  float4 w1s = reinterpret_cast<const float4*>(wt1s)[2 * l + 1];
  float4 w0d = reinterpret_cast<const float4*>(wt1d)[2 * l];
  float4 w1d = reinterpret_cast<const float4*>(wt1d)[2 * l + 1];
  float sa[4], sd[4];
  sa[0] = xv.x * w0s.x + xv.y * w1s.x;
  sa[1] = xv.x * w0s.y + xv.y * w1s.y;
  sa[2] = xv.x * w0s.z + xv.y * w1s.z;
  sa[3] = xv.x * w0s.w + xv.y * w1s.w;
  sd[0] = xv.x * w0d.x + xv.y * w1d.x;
  sd[1] = xv.x * w0d.y + xv.y * w1d.y;
  sd[2] = xv.x * w0d.z + xv.y * w1d.z;
  sd[3] = xv.x * w0d.w + xv.y * w1d.w;
#pragma unroll
  for (int o = 1; o <= 32; o <<= 1) {
#pragma unroll
    for (int h = 0; h < 4; ++h) {
      sa[h] += __shfl_xor(sa[h], o, 64);
      sd[h] += __shfl_xor(sd[h], o, 64);
    }
  }
  if (l == 0) {
#pragma unroll
    for (int h = 0; h < 4; ++h) {
      as1[n * 4 + h] = sa[h];
      ad1[n * 4 + h] = sd[h];
    }
  }
}

// ------- alpha1, SINGLE pass: p = exp(t - ln16) fp16 (shift cancels) --------
__global__ __launch_bounds__(256) void k_alpha1(const float* __restrict__ as1,
                                                const float* __restrict__ ad1,
                                                const int* __restrict__ off,
                                                const int* __restrict__ csr,
                                                _Float16* __restrict__ alpha,
                                                float* __restrict__ linv1, int N) {
  int w = threadIdx.x >> 6, lane = threadIdx.x & 63;
  int n = blockIdx.x * 4 + w;
  if (n >= N) return;
  int eidx = lane >> 2, h = lane & 3;
  float adv = ad1[n * 4 + h] - LN16;
  int e0 = off[n], e1 = off[n + 1];
  float lp = 0.f;
  for (int base = e0; base < e1; base += 16) {
    int idx = base + eidx;
    if (idx < e1) {
      int s = csr[idx];
      float t = as1[s * 4 + h] + adv;
      // leaky on the UNSHIFTED logit: t0 = t + LN16
      float t0 = t + LN16;
      t0 = t0 > 0.f ? t0 : LEAKY * t0;
      float p = __expf(t0 - LN16);
      alpha[(size_t)idx * 4 + h] = (_Float16)p;
      lp += p;
    }
  }
#pragma unroll
  for (int o = 4; o <= 32; o <<= 1) lp += __shfl_xor(lp, o, 64);
  if (lane < 4) linv1[n * 4 + h] = 1.f / lp;
}

// ---------------- x-space aggregation: packed-fp16 accumulate, 16 edges deep -
__global__ __launch_bounds__(256) void k_xagg(const _Float16* __restrict__ x16,
                                              const _Float16* __restrict__ alpha,
                                              const float* __restrict__ linv1,
                                              const int* __restrict__ off,
                                              const int* __restrict__ csr,
                                              _Float16* __restrict__ xagg, int N) {
  int w = threadIdx.x >> 6, l = threadIdx.x & 63;
  int n = blockIdx.x * 4 + w;
  if (n >= N) return;
  int slot = l >> 4, kq = l & 15;
  int e0 = off[n], e1 = off[n + 1];
  half2v acc[4][4];
#pragma unroll
  for (int h = 0; h < 4; ++h)
#pragma unroll
    for (int j = 0; j < 4; ++j) acc[h][j] = (half2v){(_Float16)0.f, (_Float16)0.f};
  const _Float16 zero16 = (_Float16)0.f;
  for (int base = e0; base < e1; base += 16) {
#pragma unroll
    for (int u = 0; u < 4; ++u) {
      int e = base + 4 * u + slot;
      int ec = min(e, e1 - 1);
      int src = csr[ec];
      half4 al = *reinterpret_cast<const half4*>(alpha + (size_t)ec * 4);
      if (e >= e1) al = (half4){zero16, zero16, zero16, zero16};
      half8 hv = *reinterpret_cast<const half8*>(x16 + (size_t)src * 128 + 8 * kq);
      half2v xp[4];
      xp[0] = (half2v){hv[0], hv[1]};
      xp[1] = (half2v){hv[2], hv[3]};
      xp[2] = (half2v){hv[4], hv[5]};
      xp[3] = (half2v){hv[6], hv[7]};
#pragma unroll
      for (int h = 0; h < 4; ++h) {
        half2v ah = (half2v){al[h], al[h]};
#pragma unroll
        for (int j = 0; j < 4; ++j) acc[h][j] = ah * xp[j] + acc[h][j];
      }
    }
  }
#pragma unroll
  for (int h = 0; h < 4; ++h)
#pragma unroll
    for (int j = 0; j < 4; ++j) {
      int v0 = __shfl_xor(__builtin_bit_cast(int, acc[h][j]), 16, 64);
      acc[h][j] = acc[h][j] + __builtin_bit_cast(half2v, v0);
      int v1 = __shfl_xor(__builtin_bit_cast(int, acc[h][j]), 32, 64);
      acc[h][j] = acc[h][j] + __builtin_bit_cast(half2v, v1);
    }
  if (slot == 0) {
    float4 linv = *reinterpret_cast<const float4*>(linv1 + n * 4);
    float rin[4] = {linv.x, linv.y, linv.z, linv.w};
#pragma unroll
    for (int h = 0; h < 4; ++h) {
      half8 o;
#pragma unroll
      for (int j = 0; j < 4; ++j) {
        o[2 * j] = (_Float16)((float)acc[h][j][0] * rin[h]);
        o[2 * j + 1] = (_Float16)((float)acc[h][j][1] * rin[h]);
      }
      *reinterpret_cast<half8*>(xagg + (size_t)n * 512 + h * 128 + 8 * kq) = o;
    }
  }
}

// -------- fused layer-1 + layer-2 GEMM: xagg -> (LDS) -> h2p, as2/ad2 --------
__global__ __launch_bounds__(256) void k_gemm12(const _Float16* __restrict__ xagg,
                                                const _Float16* __restrict__ w1hf,
                                                const _Float16* __restrict__ w2f,
                                                const float* __restrict__ b1p,
                                                const float* __restrict__ a_src2,
                                                const float* __restrict__ a_dst2,
                                                _Float16* __restrict__ h2p,
                                                float* __restrict__ as2,
                                                float* __restrict__ ad2, int N) {
  __shared__ _Float16 hs[64 * 256];  // 32 KiB
  int w = threadIdx.x >> 6, l = threadIdx.x & 63;
  int n0 = blockIdx.x * 64 + 16 * w;
  int lrow = l & 15, lgrp = l >> 4;
  int arow = min(n0 + lrow, N - 1);
  // ---- phase 1: gemm1 ----
  f32x4 acc1[4][4];
#pragma unroll
  for (int h = 0; h < 4; ++h)
#pragma unroll
    for (int ct = 0; ct < 4; ++ct) acc1[h][ct] = (f32x4){0.f, 0.f, 0.f, 0.f};
#pragma unroll
  for (int h = 0; h < 4; ++h) {
#pragma unroll
    for (int ks = 0; ks < 4; ++ks) {
      half8 af = *reinterpret_cast<const half8*>(xagg + (size_t)arow * 512 + h * 128 +
                                                 32 * ks + 8 * lgrp);
      const half8* bp =
          reinterpret_cast<const half8*>(w1hf) + (size_t)((h * 4 + ks) * 4) * 64 + l;
#pragma unroll
      for (int ct = 0; ct < 4; ++ct) {
        half8 bf = bp[ct * 64];
        acc1[h][ct] = __builtin_amdgcn_mfma_f32_16x16x32_f16(af, bf, acc1[h][ct], 0, 0, 0);
      }
    }
  }
  int lr0 = 16 * w + 4 * lgrp;
#pragma unroll
  for (int h = 0; h < 4; ++h) {
    float4 bv = *reinterpret_cast<const float4*>(b1p + h * 64 + lrow * 4);
#pragma unroll
    for (int r = 0; r < 4; ++r) {
      int row = lr0 + r;
      half4 o;
      o[0] = (_Float16)fmaxf(acc1[h][0][r] + bv.x, 0.f);
      o[1] = (_Float16)fmaxf(acc1[h][1][r] + bv.y, 0.f);
      o[2] = (_Float16)fmaxf(acc1[h][2][r] + bv.z, 0.f);
      o[3] = (_Float16)fmaxf(acc1[h][3][r] + bv.w, 0.f);
      int ba = row * 512 + ((h * 128 + lrow * 8) ^ ((row & 7) << 4));
      *reinterpret_cast<half4*>(reinterpret_cast<char*>(hs) + ba) = o;
    }
  }
  __syncthreads();
  // ---- phase 2: gemm2 over K=256 from LDS ----
  int arow2 = 16 * w + lrow;
  f32x4 acc2[4];
#pragma unroll
  for (int ct = 0; ct < 4; ++ct) acc2[ct] = (f32x4){0.f, 0.f, 0.f, 0.f};
#pragma unroll
  for (int ks = 0; ks < 8; ++ks) {
    int ba = arow2 * 512 + ((64 * ks + 16 * lgrp) ^ ((arow2 & 7) << 4));
    half8 af = *reinterpret_cast<const half8*>(reinterpret_cast<const char*>(hs) + ba);
    const half8* bp = reinterpret_cast<const half8*>(w2f) + (size_t)(ks * 4) * 64 + l;
#pragma unroll
    for (int ct = 0; ct < 4; ++ct) {
      half8 bf = bp[ct * 64];
      acc2[ct] = __builtin_amdgcn_mfma_f32_16x16x32_f16(af, bf, acc2[ct], 0, 0, 0);
    }
  }
  float ascol[4], adcol[4];
#pragma unroll
  for (int ct = 0; ct < 4; ++ct) {
    ascol[ct] = a_src2[16 * ct + lrow];
    adcol[ct] = a_dst2[16 * ct + lrow];
  }
  int rbase = n0 + 4 * lgrp;
#pragma unroll
  for (int r = 0; r < 4; ++r) {
    int row = rbase + r;
    bool ok = row < N;
    float sa = 0.f, sd = 0.f;
    half4 o;
#pragma unroll
    for (int ct = 0; ct < 4; ++ct) {
      float v = acc2[ct][r];
      o[ct] = (_Float16)v;
      sa = fmaf(v, ascol[ct], sa);
      sd = fmaf(v, adcol[ct], sd);
    }
    if (ok) *reinterpret_cast<half4*>(h2p + (size_t)row * 64 + lrow * 4) = o;
#pragma unroll
    for (int oo = 1; oo <= 8; oo <<= 1) {
      sa += __shfl_xor(sa, oo, 64);
      sd += __shfl_xor(sd, oo, 64);
    }
    if (ok && lrow == 0) {
      as2[row] = sa;
      ad2[row] = sd;
    }
  }
}

// ---------------- Layer 2: fused softmax + aggregation, SINGLE pass ---------
// p = expf(t) in fp32 (no max; overflow needs t>88, logits are O(1)).
__global__ __launch_bounds__(256) void k_agg2(const _Float16* __restrict__ h2p,
                                              const float* __restrict__ as2,
                                              const float* __restrict__ ad2,
                                              const float* __restrict__ b2,
                                              const int* __restrict__ off,
                                              const int* __restrict__ csr,
                                              float* __restrict__ out, int N) {
  int w = threadIdx.x >> 6, lane = threadIdx.x & 63;
  int n = blockIdx.x * 4 + w;
  if (n >= N) return;
  float adv = ad2[n];
  int e0 = off[n], e1 = off[n + 1];
  int slot = lane >> 3, q = lane & 7;
  float acc[8];
  float lp = 0.f;
#pragma unroll
  for (int k = 0; k < 8; ++k) acc[k] = 0.f;
  for (int base = e0; base < e1; base += 16) {
#pragma unroll
    for (int u = 0; u < 2; ++u) {
      int e = base + 8 * u + slot;
      int ec = min(e, e1 - 1);
      int s = csr[ec];
      float t = as2[s] + adv;
      t = t > 0.f ? t : LEAKY * t;
      float p = (e < e1) ? __expf(t) : 0.f;
      lp += p;
      half8 hv = *reinterpret_cast<const half8*>(h2p + (size_t)s * 64 + 8 * q);
#pragma unroll
      for (int k = 0; k < 8; ++k) acc[k] = fmaf(p, (float)hv[k], acc[k]);
    }
  }
#pragma unroll
  for (int o = 8; o <= 32; o <<= 1) {
    lp += __shfl_xor(lp, o, 64);
#pragma unroll
    for (int k = 0; k < 8; ++k) acc[k] += __shfl_xor(acc[k], o, 64);
  }
  if (slot == 0) {
    float rinv = 1.f / lp;
    // storage p = 8q + k  ->  orig col = ((k&3)<<4) | (2q + (k>>2))
#pragma unroll
    for (int k = 0; k < 8; ++k) {
      int col = ((k & 3) << 4) + 2 * q + (k >> 2);
      out[(size_t)n * 64 + col] = acc[k] * rinv + b2[col];
    }
  }
}

extern "C" void kernel_launch(void* const* d_in, const int* in_sizes, int n_in,
                              void* d_out, int out_size, void* d_ws, size_t ws_size,
                              hipStream_t stream) {
  const float* x = (const float*)d_in[0];
  const int* ei = (const int*)d_in[1];
  const float* W1 = (const float*)d_in[2];
  const float* a_src1 = (const float*)d_in[3];
  const float* a_dst1 = (const float*)d_in[4];
  const float* b1 = (const float*)d_in[5];
  const float* W2 = (const float*)d_in[6];
  const float* a_src2 = (const float*)d_in[7];
  const float* a_dst2 = (const float*)d_in[8];
  const float* b2 = (const float*)d_in[9];
  float* out = (float*)d_out;

  const int N = in_sizes[0] / 128;
  const int NE = in_sizes[1] / 2;
  const int ET = NE + N;
  const int chunk = ceil_div(N, SB);
  const int cap = 3 * ceil_div(ET, SB);

  char* p = (char*)d_ws;
  auto alloc = [&](size_t bytes) {
    char* r = p;
    p += (bytes + 255) & ~(size_t)255;
    return r;
  };
  int* bcnt = (int*)alloc((size_t)SB * 4);
  int* off = (int*)alloc((size_t)(N + 1) * 4);
  int* csr = (int*)alloc((size_t)ET * 4);
  unsigned* pairs = (unsigned*)alloc((size_t)SB * cap * 4);
  _Float16* w1hf = (_Float16*)alloc((size_t)32768 * 2);
  _Float16* w2f = (_Float16*)alloc((size_t)16384 * 2);
  float* wt1s = (float*)alloc((size_t)512 * 4);
  float* wt1d = (float*)alloc((size_t)512 * 4);
  float* b1p = (float*)alloc((size_t)256 * 4);
  _Float16* x16 = (_Float16*)alloc((size_t)N * 128 * 2);
  _Float16* xagg = (_Float16*)alloc((size_t)N * 512 * 2);
  float* as1 = (float*)alloc((size_t)N * 4 * 4);
  float* ad1 = (float*)alloc((size_t)N * 4 * 4);
  _Float16* alpha1 = (_Float16*)alloc((size_t)ET * 4 * 2);
  float* linv1 = (float*)alloc((size_t)N * 4 * 4);
  _Float16* h2p = x16;  // reuse: x16 dead after k_xagg
  float* as2 = (float*)alloc((size_t)N * 4);
  float* ad2 = (float*)alloc((size_t)N * 4);

  k_zero<<<1, 256, 0, stream>>>((int4*)bcnt, SB / 4);
  k_fillA<<<ceil_div(ET, FTILE), 256, 0, stream>>>(ei, bcnt, pairs, NE, N, chunk, cap);
  k_fillB2<<<SB, 256, 0, stream>>>(pairs, bcnt, off, csr, N, chunk, cap);
  k_prep<<<198, 256, 0, stream>>>(W1, W2, a_src1, a_dst1, a_src2, a_dst2, b1,
                                  w1hf, w2f, wt1s, wt1d, b1p);

  k_logits1<<<ceil_div(N, 4), 256, 0, stream>>>(x, wt1s, wt1d, x16, as1, ad1, N);
  k_alpha1<<<ceil_div(N, 4), 256, 0, stream>>>(as1, ad1, off, csr, alpha1, linv1, N);
  k_xagg<<<ceil_div(N, 4), 256, 0, stream>>>(x16, alpha1, linv1, off, csr, xagg, N);
  k_gemm12<<<ceil_div(N, 64), 256, 0, stream>>>(xagg, w1hf, w2f, b1p, a_src2,
                                                a_dst2, h2p, as2, ad2, N);
  k_agg2<<<ceil_div(N, 4), 256, 0, stream>>>(h2p, as2, ad2, b2, off, csr, out, N);
}

// Round 19
// 173.856 us; speedup vs baseline: 1.1101x; 1.0224x over previous
//
#include <hip/hip_runtime.h>
#include <math.h>

#define LEAKY 0.2f
#define SB 256
#define FTILE 4096
#define LN16 2.7725887f

typedef _Float16 half2v __attribute__((ext_vector_type(2)));
typedef _Float16 half4 __attribute__((ext_vector_type(4)));
typedef _Float16 half8 __attribute__((ext_vector_type(8)));
typedef float f32x4 __attribute__((ext_vector_type(4)));

static inline int ceil_div(int a, int b) { return (a + b - 1) / b; }

// storage index p -> original column, for 64-col groups
__device__ __forceinline__ int PERM(int p) {
  int q = p & 63;
  return (p & ~63) | (((q & 3) << 4) | (q >> 2));
}

// ---- fillA: radix-partition edges into bucket-contiguous packed pairs ------
__global__ __launch_bounds__(256) void k_fillA(const int* __restrict__ ei,
                                               int* __restrict__ bcnt,
                                               unsigned* __restrict__ pairs,
                                               int NE, int N, int chunk, int cap) {
  __shared__ int hist[256], base[256], cnt2[256];
  int t = threadIdx.x;
  hist[t] = 0;
  cnt2[t] = 0;
  __syncthreads();
  int ET = NE + N;
  int e0 = blockIdx.x * FTILE;
  int e1 = min(e0 + FTILE, ET);
  for (int e = e0 + t; e < e1; e += 256) {
    int d = (e < NE) ? ei[NE + e] : (e - NE);
    atomicAdd(&hist[d / chunk], 1);
  }
  __syncthreads();
  if (hist[t] > 0) base[t] = t * cap + atomicAdd(&bcnt[t], hist[t]);
  __syncthreads();
  for (int e = e0 + t; e < e1; e += 256) {
    int s = (e < NE) ? ei[e] : (e - NE);
    int d = (e < NE) ? ei[NE + e] : (e - NE);
    int b = d / chunk;
    int r = atomicAdd(&cnt2[b], 1);
    pairs[base[b] + r] = ((unsigned)(d - b * chunk) << 20) | (unsigned)s;
  }
}

// ---- fillB2: inline bcnt scan + per-bucket local degree + off + csr scatter -
__global__ __launch_bounds__(256) void k_fillB2(const unsigned* __restrict__ pairs,
                                                const int* __restrict__ bcnt,
                                                int* __restrict__ off,
                                                int* __restrict__ csr, int N,
                                                int chunk, int cap) {
  __shared__ int sc[256], hist[256], cur[256];
  int b = blockIdx.x, t = threadIdx.x;
  int node0 = b * chunk;
  int bv = bcnt[t];
  sc[t] = bv;
  __syncthreads();
  for (int o = 1; o < 256; o <<= 1) {
    int u = (t >= o) ? sc[t - o] : 0;
    __syncthreads();
    sc[t] += u;
    __syncthreads();
  }
  int bpre_b = sc[b] - bcnt[b];
  int total = sc[255];
  if (t == 0 && b == (N - 1) / chunk) off[N] = total;
  hist[t] = 0;
  __syncthreads();
  int i0 = b * cap, i1 = i0 + bcnt[b];
  for (int i = i0 + t; i < i1; i += 256)
    atomicAdd(&hist[pairs[i] >> 20], 1);
  __syncthreads();
  int v = hist[t];
  for (int o = 1; o < 256; o <<= 1) {
    int u = (t >= o) ? hist[t - o] : 0;
    __syncthreads();
    hist[t] += u;
    __syncthreads();
  }
  int ex = hist[t] - v + bpre_b;
  if (t < chunk && node0 + t < N) off[node0 + t] = ex;
  cur[t] = ex;
  __syncthreads();
  for (int i = i0 + t; i < i1; i += 256) {
    unsigned u = pairs[i];
    int pos = atomicAdd(&cur[u >> 20], 1);
    csr[pos] = (int)(u & 0xFFFFFu);
  }
}

// ------- prep: weight fragments + folded attention vectors + bcnt zero -------
// launched FIRST (input-independent); spare tail threads zero bcnt for fillA.
__global__ __launch_bounds__(256) void k_prep(const float* __restrict__ W1,
                                              const float* __restrict__ W2,
                                              const float* __restrict__ a_src1,
                                              const float* __restrict__ a_dst1,
                                              const float* __restrict__ a_src2,
                                              const float* __restrict__ a_dst2,
                                              const float* __restrict__ b1,
                                              _Float16* __restrict__ w1hf,
                                              _Float16* __restrict__ w2f,
                                              float* __restrict__ wt1s,
                                              float* __restrict__ wt1d,
                                              float* __restrict__ b1p,
                                              int* __restrict__ bcnt) {
  int idx = blockIdx.x * 256 + threadIdx.x;
  if (idx < 32768) {  // w1hf[h][ks][ct][l][i]
    int i = idx & 7, l = (idx >> 3) & 63, ct = (idx >> 9) & 3, ks = (idx >> 11) & 3,
        h = idx >> 13;
    int k = 32 * ks + 8 * (l >> 4) + i;
    int col = h * 64 + 16 * ct + (l & 15);
    w1hf[idx] = (_Float16)W1[k * 256 + col];
    return;
  }
  int i2 = idx - 32768;
  if (i2 < 16384) {  // w2f[ks][ct][l][i], A-side k' is layer-1 permuted index
    int i = i2 & 7, l = (i2 >> 3) & 63, ct = (i2 >> 9) & 3, ks = i2 >> 11;
    int kp = 32 * ks + 8 * (l >> 4) + i;
    int col = 16 * ct + (l & 15);
    w2f[i2] = (_Float16)W2[PERM(kp) * 64 + col];
    return;
  }
  int i3 = i2 - 16384;
  if (i3 < 512) {  // wt1s/wt1d[k*4+h]
    int h = i3 & 3, k = i3 >> 2;
    float ss = 0.f, sd = 0.f;
    for (int d = 0; d < 64; ++d) {
      float wv = W1[k * 256 + h * 64 + d];
      ss = fmaf(wv, a_src1[h * 64 + d], ss);
      sd = fmaf(wv, a_dst1[h * 64 + d], sd);
    }
    wt1s[i3] = ss;
    wt1d[i3] = sd;
    return;
  }
  int i4 = i3 - 512;
  if (i4 < 256) {
    b1p[i4] = b1[PERM(i4)];
    return;
  }
  int i5 = i4 - 256;
  if (i5 < 256) bcnt[i5] = 0;
}

// ---------------- logits1: as1/ad1 = x @ wt1, also emit x16 -----------------
__global__ __launch_bounds__(256) void k_logits1(const float* __restrict__ x,
                                                 const float* __restrict__ wt1s,
                                                 const float* __restrict__ wt1d,
                                                 _Float16* __restrict__ x16,
                                                 float* __restrict__ as1,
                                                 float* __restrict__ ad1, int N) {
  int w = threadIdx.x >> 6, l = threadIdx.x & 63;
  int n = blockIdx.x * 4 + w;
  if (n >= N) return;
  float2 xv = *reinterpret_cast<const float2*>(x + (size_t)n * 128 + 2 * l);
  half2v xh;
  xh[0] = (_Float16)xv.x;
  xh[1] = (_Float16)xv.y;
  *reinterpret_cast<half2v*>(x16 + (size_t)n * 128 + 2 * l) = xh;
  float4 w0s = reinterpret_cast<const float4*>(wt1s)[2 * l];
  float4 w1s = reinterpret_cast<const float4*>(wt1s)[2 * l + 1];
  float4 w0d = reinterpret_cast<const float4*>(wt1d)[2 * l];
  float4 w1d = reinterpret_cast<const float4*>(wt1d)[2 * l + 1];
  float sa[4], sd[4];
  sa[0] = xv.x * w0s.x + xv.y * w1s.x;
  sa[1] = xv.x * w0s.y + xv.y * w1s.y;
  sa[2] = xv.x * w0s.z + xv.y * w1s.z;
  sa[3] = xv.x * w0s.w + xv.y * w1s.w;
  sd[0] = xv.x * w0d.x + xv.y * w1d.x;
  sd[1] = xv.x * w0d.y + xv.y * w1d.y;
  sd[2] = xv.x * w0d.z + xv.y * w1d.z;
  sd[3] = xv.x * w0d.w + xv.y * w1d.w;
#pragma unroll
  for (int o = 1; o <= 32; o <<= 1) {
#pragma unroll
    for (int h = 0; h < 4; ++h) {
      sa[h] += __shfl_xor(sa[h], o, 64);
      sd[h] += __shfl_xor(sd[h], o, 64);
    }
  }
  if (l == 0) {
#pragma unroll
    for (int h = 0; h < 4; ++h) {
      as1[n * 4 + h] = sa[h];
      ad1[n * 4 + h] = sd[h];
    }
  }
}

// ------- alpha1, SINGLE pass: p = exp(t - ln16) fp16 (shift cancels) --------
__global__ __launch_bounds__(256) void k_alpha1(const float* __restrict__ as1,
                                                const float* __restrict__ ad1,
                                                const int* __restrict__ off,
                                                const int* __restrict__ csr,
                                                _Float16* __restrict__ alpha,
                                                float* __restrict__ linv1, int N) {
  int w = threadIdx.x >> 6, lane = threadIdx.x & 63;
  int n = blockIdx.x * 4 + w;
  if (n >= N) return;
  int eidx = lane >> 2, h = lane & 3;
  float adv = ad1[n * 4 + h] - LN16;
  int e0 = off[n], e1 = off[n + 1];
  float lp = 0.f;
  for (int base = e0; base < e1; base += 16) {
    int idx = base + eidx;
    if (idx < e1) {
      int s = csr[idx];
      float t = as1[s * 4 + h] + adv;
      float t0 = t + LN16;
      t0 = t0 > 0.f ? t0 : LEAKY * t0;
      float p = __expf(t0 - LN16);
      alpha[(size_t)idx * 4 + h] = (_Float16)p;
      lp += p;
    }
  }
#pragma unroll
  for (int o = 4; o <= 32; o <<= 1) lp += __shfl_xor(lp, o, 64);
  if (lane < 4) linv1[n * 4 + h] = 1.f / lp;
}

// ---------------- x-space aggregation: packed-fp16 accumulate, 16 edges deep -
__global__ __launch_bounds__(256) void k_xagg(const _Float16* __restrict__ x16,
                                              const _Float16* __restrict__ alpha,
                                              const float* __restrict__ linv1,
                                              const int* __restrict__ off,
                                              const int* __restrict__ csr,
                                              _Float16* __restrict__ xagg, int N) {
  int w = threadIdx.x >> 6, l = threadIdx.x & 63;
  int n = blockIdx.x * 4 + w;
  if (n >= N) return;
  int slot = l >> 4, kq = l & 15;
  int e0 = off[n], e1 = off[n + 1];
  half2v acc[4][4];
#pragma unroll
  for (int h = 0; h < 4; ++h)
#pragma unroll
    for (int j = 0; j < 4; ++j) acc[h][j] = (half2v){(_Float16)0.f, (_Float16)0.f};
  const _Float16 zero16 = (_Float16)0.f;
  for (int base = e0; base < e1; base += 16) {
#pragma unroll
    for (int u = 0; u < 4; ++u) {
      int e = base + 4 * u + slot;
      int ec = min(e, e1 - 1);
      int src = csr[ec];
      half4 al = *reinterpret_cast<const half4*>(alpha + (size_t)ec * 4);
      if (e >= e1) al = (half4){zero16, zero16, zero16, zero16};
      half8 hv = *reinterpret_cast<const half8*>(x16 + (size_t)src * 128 + 8 * kq);
      half2v xp[4];
      xp[0] = (half2v){hv[0], hv[1]};
      xp[1] = (half2v){hv[2], hv[3]};
      xp[2] = (half2v){hv[4], hv[5]};
      xp[3] = (half2v){hv[6], hv[7]};
#pragma unroll
      for (int h = 0; h < 4; ++h) {
        half2v ah = (half2v){al[h], al[h]};
#pragma unroll
        for (int j = 0; j < 4; ++j) acc[h][j] = ah * xp[j] + acc[h][j];
      }
    }
  }
#pragma unroll
  for (int h = 0; h < 4; ++h)
#pragma unroll
    for (int j = 0; j < 4; ++j) {
      int v0 = __shfl_xor(__builtin_bit_cast(int, acc[h][j]), 16, 64);
      acc[h][j] = acc[h][j] + __builtin_bit_cast(half2v, v0);
      int v1 = __shfl_xor(__builtin_bit_cast(int, acc[h][j]), 32, 64);
      acc[h][j] = acc[h][j] + __builtin_bit_cast(half2v, v1);
    }
  if (slot == 0) {
    float4 linv = *reinterpret_cast<const float4*>(linv1 + n * 4);
    float rin[4] = {linv.x, linv.y, linv.z, linv.w};
#pragma unroll
    for (int h = 0; h < 4; ++h) {
      half8 o;
#pragma unroll
      for (int j = 0; j < 4; ++j) {
        o[2 * j] = (_Float16)((float)acc[h][j][0] * rin[h]);
        o[2 * j + 1] = (_Float16)((float)acc[h][j][1] * rin[h]);
      }
      *reinterpret_cast<half8*>(xagg + (size_t)n * 512 + h * 128 + 8 * kq) = o;
    }
  }
}

// -------- fused layer-1 + layer-2 GEMM: xagg -> (LDS) -> h2p, as2/ad2 --------
__global__ __launch_bounds__(256) void k_gemm12(const _Float16* __restrict__ xagg,
                                                const _Float16* __restrict__ w1hf,
                                                const _Float16* __restrict__ w2f,
                                                const float* __restrict__ b1p,
                                                const float* __restrict__ a_src2,
                                                const float* __restrict__ a_dst2,
                                                _Float16* __restrict__ h2p,
                                                float* __restrict__ as2,
                                                float* __restrict__ ad2, int N) {
  __shared__ _Float16 hs[64 * 256];  // 32 KiB
  int w = threadIdx.x >> 6, l = threadIdx.x & 63;
  int n0 = blockIdx.x * 64 + 16 * w;
  int lrow = l & 15, lgrp = l >> 4;
  int arow = min(n0 + lrow, N - 1);
  // ---- phase 1: gemm1 ----
  f32x4 acc1[4][4];
#pragma unroll
  for (int h = 0; h < 4; ++h)
#pragma unroll
    for (int ct = 0; ct < 4; ++ct) acc1[h][ct] = (f32x4){0.f, 0.f, 0.f, 0.f};
#pragma unroll
  for (int h = 0; h < 4; ++h) {
#pragma unroll
    for (int ks = 0; ks < 4; ++ks) {
      half8 af = *reinterpret_cast<const half8*>(xagg + (size_t)arow * 512 + h * 128 +
                                                 32 * ks + 8 * lgrp);
      const half8* bp =
          reinterpret_cast<const half8*>(w1hf) + (size_t)((h * 4 + ks) * 4) * 64 + l;
#pragma unroll
      for (int ct = 0; ct < 4; ++ct) {
        half8 bf = bp[ct * 64];
        acc1[h][ct] = __builtin_amdgcn_mfma_f32_16x16x32_f16(af, bf, acc1[h][ct], 0, 0, 0);
      }
    }
  }
  int lr0 = 16 * w + 4 * lgrp;
#pragma unroll
  for (int h = 0; h < 4; ++h) {
    float4 bv = *reinterpret_cast<const float4*>(b1p + h * 64 + lrow * 4);
#pragma unroll
    for (int r = 0; r < 4; ++r) {
      int row = lr0 + r;
      half4 o;
      o[0] = (_Float16)fmaxf(acc1[h][0][r] + bv.x, 0.f);
      o[1] = (_Float16)fmaxf(acc1[h][1][r] + bv.y, 0.f);
      o[2] = (_Float16)fmaxf(acc1[h][2][r] + bv.z, 0.f);
      o[3] = (_Float16)fmaxf(acc1[h][3][r] + bv.w, 0.f);
      int ba = row * 512 + ((h * 128 + lrow * 8) ^ ((row & 7) << 4));
      *reinterpret_cast<half4*>(reinterpret_cast<char*>(hs) + ba) = o;
    }
  }
  __syncthreads();
  // ---- phase 2: gemm2 over K=256 from LDS ----
  int arow2 = 16 * w + lrow;
  f32x4 acc2[4];
#pragma unroll
  for (int ct = 0; ct < 4; ++ct) acc2[ct] = (f32x4){0.f, 0.f, 0.f, 0.f};
#pragma unroll
  for (int ks = 0; ks < 8; ++ks) {
    int ba = arow2 * 512 + ((64 * ks + 16 * lgrp) ^ ((arow2 & 7) << 4));
    half8 af = *reinterpret_cast<const half8*>(reinterpret_cast<const char*>(hs) + ba);
    const half8* bp = reinterpret_cast<const half8*>(w2f) + (size_t)(ks * 4) * 64 + l;
#pragma unroll
    for (int ct = 0; ct < 4; ++ct) {
      half8 bf = bp[ct * 64];
      acc2[ct] = __builtin_amdgcn_mfma_f32_16x16x32_f16(af, bf, acc2[ct], 0, 0, 0);
    }
  }
  float ascol[4], adcol[4];
#pragma unroll
  for (int ct = 0; ct < 4; ++ct) {
    ascol[ct] = a_src2[16 * ct + lrow];
    adcol[ct] = a_dst2[16 * ct + lrow];
  }
  int rbase = n0 + 4 * lgrp;
#pragma unroll
  for (int r = 0; r < 4; ++r) {
    int row = rbase + r;
    bool ok = row < N;
    float sa = 0.f, sd = 0.f;
    half4 o;
#pragma unroll
    for (int ct = 0; ct < 4; ++ct) {
      float v = acc2[ct][r];
      o[ct] = (_Float16)v;
      sa = fmaf(v, ascol[ct], sa);
      sd = fmaf(v, adcol[ct], sd);
    }
    if (ok) *reinterpret_cast<half4*>(h2p + (size_t)row * 64 + lrow * 4) = o;
#pragma unroll
    for (int oo = 1; oo <= 8; oo <<= 1) {
      sa += __shfl_xor(sa, oo, 64);
      sd += __shfl_xor(sd, oo, 64);
    }
    if (ok && lrow == 0) {
      as2[row] = sa;
      ad2[row] = sd;
    }
  }
}

// ---------------- Layer 2: fused softmax + aggregation, SINGLE pass ---------
__global__ __launch_bounds__(256) void k_agg2(const _Float16* __restrict__ h2p,
                                              const float* __restrict__ as2,
                                              const float* __restrict__ ad2,
                                              const float* __restrict__ b2,
                                              const int* __restrict__ off,
                                              const int* __restrict__ csr,
                                              float* __restrict__ out, int N) {
  int w = threadIdx.x >> 6, lane = threadIdx.x & 63;
  int n = blockIdx.x * 4 + w;
  if (n >= N) return;
  float adv = ad2[n];
  int e0 = off[n], e1 = off[n + 1];
  int slot = lane >> 3, q = lane & 7;
  float acc[8];
  float lp = 0.f;
#pragma unroll
  for (int k = 0; k < 8; ++k) acc[k] = 0.f;
  for (int base = e0; base < e1; base += 16) {
#pragma unroll
    for (int u = 0; u < 2; ++u) {
      int e = base + 8 * u + slot;
      int ec = min(e, e1 - 1);
      int s = csr[ec];
      float t = as2[s] + adv;
      t = t > 0.f ? t : LEAKY * t;
      float p = (e < e1) ? __expf(t) : 0.f;
      lp += p;
      half8 hv = *reinterpret_cast<const half8*>(h2p + (size_t)s * 64 + 8 * q);
#pragma unroll
      for (int k = 0; k < 8; ++k) acc[k] = fmaf(p, (float)hv[k], acc[k]);
    }
  }
#pragma unroll
  for (int o = 8; o <= 32; o <<= 1) {
    lp += __shfl_xor(lp, o, 64);
#pragma unroll
    for (int k = 0; k < 8; ++k) acc[k] += __shfl_xor(acc[k], o, 64);
  }
  if (slot == 0) {
    float rinv = 1.f / lp;
    // storage p = 8q + k  ->  orig col = ((k&3)<<4) | (2q + (k>>2))
#pragma unroll
    for (int k = 0; k < 8; ++k) {
      int col = ((k & 3) << 4) + 2 * q + (k >> 2);
      out[(size_t)n * 64 + col] = acc[k] * rinv + b2[col];
    }
  }
}

extern "C" void kernel_launch(void* const* d_in, const int* in_sizes, int n_in,
                              void* d_out, int out_size, void* d_ws, size_t ws_size,
                              hipStream_t stream) {
  const float* x = (const float*)d_in[0];
  const int* ei = (const int*)d_in[1];
  const float* W1 = (const float*)d_in[2];
  const float* a_src1 = (const float*)d_in[3];
  const float* a_dst1 = (const float*)d_in[4];
  const float* b1 = (const float*)d_in[5];
  const float* W2 = (const float*)d_in[6];
  const float* a_src2 = (const float*)d_in[7];
  const float* a_dst2 = (const float*)d_in[8];
  const float* b2 = (const float*)d_in[9];
  float* out = (float*)d_out;

  const int N = in_sizes[0] / 128;
  const int NE = in_sizes[1] / 2;
  const int ET = NE + N;
  const int chunk = ceil_div(N, SB);
  const int cap = 3 * ceil_div(ET, SB);

  char* p = (char*)d_ws;
  auto alloc = [&](size_t bytes) {
    char* r = p;
    p += (bytes + 255) & ~(size_t)255;
    return r;
  };
  int* bcnt = (int*)alloc((size_t)SB * 4);
  int* off = (int*)alloc((size_t)(N + 1) * 4);
  int* csr = (int*)alloc((size_t)ET * 4);
  unsigned* pairs = (unsigned*)alloc((size_t)SB * cap * 4);
  _Float16* w1hf = (_Float16*)alloc((size_t)32768 * 2);
  _Float16* w2f = (_Float16*)alloc((size_t)16384 * 2);
  float* wt1s = (float*)alloc((size_t)512 * 4);
  float* wt1d = (float*)alloc((size_t)512 * 4);
  float* b1p = (float*)alloc((size_t)256 * 4);
  _Float16* x16 = (_Float16*)alloc((size_t)N * 128 * 2);
  _Float16* xagg = (_Float16*)alloc((size_t)N * 512 * 2);
  float* as1 = (float*)alloc((size_t)N * 4 * 4);
  float* ad1 = (float*)alloc((size_t)N * 4 * 4);
  _Float16* alpha1 = (_Float16*)alloc((size_t)ET * 4 * 2);
  float* linv1 = (float*)alloc((size_t)N * 4 * 4);
  _Float16* h2p = x16;  // reuse: x16 dead after k_xagg
  float* as2 = (float*)alloc((size_t)N * 4);
  float* ad2 = (float*)alloc((size_t)N * 4);

  // prep first (input-independent); its tail threads zero bcnt for fillA.
  k_prep<<<198, 256, 0, stream>>>(W1, W2, a_src1, a_dst1, a_src2, a_dst2, b1,
                                  w1hf, w2f, wt1s, wt1d, b1p, bcnt);
  k_fillA<<<ceil_div(ET, FTILE), 256, 0, stream>>>(ei, bcnt, pairs, NE, N, chunk, cap);
  k_fillB2<<<SB, 256, 0, stream>>>(pairs, bcnt, off, csr, N, chunk, cap);

  k_logits1<<<ceil_div(N, 4), 256, 0, stream>>>(x, wt1s, wt1d, x16, as1, ad1, N);
  k_alpha1<<<ceil_div(N, 4), 256, 0, stream>>>(as1, ad1, off, csr, alpha1, linv1, N);
  k_xagg<<<ceil_div(N, 4), 256, 0, stream>>>(x16, alpha1, linv1, off, csr, xagg, N);
  k_gemm12<<<ceil_div(N, 64), 256, 0, stream>>>(xagg, w1hf, w2f, b1p, a_src2,
                                                a_dst2, h2p, as2, ad2, N);
  k_agg2<<<ceil_div(N, 4), 256, 0, stream>>>(h2p, as2, ad2, b2, off, csr, out, N);
}